// Round 7
// baseline (1378.338 us; speedup 1.0000x reference)
//
#include <hip/hip_runtime.h>
#include <hip/hip_bf16.h>

// Problem constants (fixed by the reference file).
#define K_OFF 27
#define M_PTS 100000
#define KM (K_OFF * M_PTS)      // 2,700,000 contributions
#define C_CH 64
#define N_OUT_PTS 400000
#define BN_EPS 1e-5f
#define N_TILES (N_OUT_PTS / 16)   // 25000 output tiles of 16 rows
#define GBLOCKS (N_TILES / 4)      // 6250 gather blocks: 4 waves, 1 tile/wave
#define SRC_MASK 0x3FFFF           // entries pack (k<<18)|src, src<200000<2^18

typedef __attribute__((ext_vector_type(8))) short short8;  // 8 bf16 = 4 VGPRs
typedef __attribute__((ext_vector_type(4))) float f32x4;

__device__ inline short bf16c(float f) {
    return __builtin_bit_cast(short, __float2bfloat16(f));
}

// Packed 2xbf16 atomic add (fallback path only).
__device__ inline void pk_atomic_add_bf16(__hip_bfloat16* p, int bits) {
#if __has_builtin(__builtin_amdgcn_global_atomic_fadd_v2bf16)
    typedef short s2v __attribute__((ext_vector_type(2)));
    typedef __attribute__((address_space(1))) s2v* gp;
    s2v v;
    __builtin_memcpy(&v, &bits, 4);
    __builtin_amdgcn_global_atomic_fadd_v2bf16((gp)(unsigned long long)p, v);
#else
    asm volatile("global_atomic_pk_add_bf16 %0, %1, off"
                 :: "v"((unsigned long long)p), "v"(bits) : "memory");
#endif
}

__device__ inline unsigned bytesum(unsigned v) {
    return (v & 255u) + ((v >> 8) & 255u) + ((v >> 16) & 255u) + (v >> 24);
}

// ===========================================================================
// x fp32 -> bf16, SWIZZLED per row so lane g's per-entry 32B is contiguous:
// x16[row*64 + g*16 + 0..7]  = cin[8g .. 8g+7]       (af0 slice)
// x16[row*64 + g*16 + 8..15] = cin[32+8g .. 32+8g+7] (af1 slice)
// ===========================================================================
__global__ __launch_bounds__(256) void xconv(
    const float* __restrict__ x, unsigned short* __restrict__ x16)
{
    int t = blockIdx.x * 256 + threadIdx.x;   // (row, g); 800000 total
    if (t >= 200000 * 4) return;
    int row = t >> 2, g = t & 3;
    const float* __restrict__ in = x + (size_t)row * C_CH;
    short8 v0, v1;
    #pragma unroll
    for (int j = 0; j < 8; ++j) {
        v0[j] = bf16c(in[8 * g + j]);
        v1[j] = bf16c(in[32 + 8 * g + j]);
    }
    unsigned short* o = x16 + (size_t)row * C_CH + g * 16;
    *(short8*)o = v0;
    *(short8*)(o + 8) = v1;
}

// ===========================================================================
// CSR construction: per-(row,k) byte-packed histogram -> scan -> k-sorted fill
// ===========================================================================

__global__ __launch_bounds__(256) void hist_kernel(
    const int* __restrict__ out_idx, unsigned* __restrict__ hist)
{
    int i = blockIdx.x * 256 + threadIdx.x;
    if (i >= KM) return;
    int row = out_idx[i];
    int k = i / M_PTS;
    atomicAdd(&hist[(size_t)row * 8 + (k >> 2)], 1u << (8 * (k & 3)));
}

__global__ __launch_bounds__(256) void scan_a(
    const unsigned* __restrict__ hist, int* __restrict__ partial,
    int* __restrict__ blockSums)
{
    __shared__ int sh[256];
    const int t = threadIdx.x, b = blockIdx.x;
    const int r0 = b * 1024 + t * 4;
    int cnt[4] = {0, 0, 0, 0};
    if (r0 < N_OUT_PTS) {
        #pragma unroll
        for (int u = 0; u < 4; ++u) {
            const uint4* hp = (const uint4*)(hist + (size_t)(r0 + u) * 8);
            uint4 a = hp[0], bq = hp[1];
            cnt[u] = (int)(bytesum(a.x) + bytesum(a.y) + bytesum(a.z) + bytesum(a.w) +
                           bytesum(bq.x) + bytesum(bq.y) + bytesum(bq.z) + bytesum(bq.w));
        }
    }
    int tsum = cnt[0] + cnt[1] + cnt[2] + cnt[3];
    sh[t] = tsum;
    __syncthreads();
    for (int o = 1; o < 256; o <<= 1) {
        int u = (t >= o) ? sh[t - o] : 0;
        __syncthreads();
        sh[t] += u;
        __syncthreads();
    }
    int excl = sh[t] - tsum;
    if (r0 < N_OUT_PTS) {
        partial[r0]     = excl;
        partial[r0 + 1] = excl + cnt[0];
        partial[r0 + 2] = excl + cnt[0] + cnt[1];
        partial[r0 + 3] = excl + cnt[0] + cnt[1] + cnt[2];
    }
    if (t == 255) blockSums[b] = sh[255];
}

#define SCAN_BLOCKS ((N_OUT_PTS + 1023) / 1024)   // 391

__global__ __launch_bounds__(512) void scan_b(
    const int* __restrict__ blockSums, int* __restrict__ blockOff)
{
    __shared__ int sh[512];
    const int t = threadIdx.x;
    int v = (t < SCAN_BLOCKS) ? blockSums[t] : 0;
    sh[t] = v;
    __syncthreads();
    for (int o = 1; o < 512; o <<= 1) {
        int u = (t >= o) ? sh[t - o] : 0;
        __syncthreads();
        sh[t] += u;
        __syncthreads();
    }
    if (t < SCAN_BLOCKS) blockOff[t] = sh[t] - v;
}

__global__ __launch_bounds__(256) void fill_kernel(
    const int* __restrict__ out_idx, const int* __restrict__ in_idx,
    const unsigned* __restrict__ hist, unsigned* __restrict__ cursor,
    const int* __restrict__ partial, const int* __restrict__ blockOff,
    int* __restrict__ entries)
{
    int i = blockIdx.x * 256 + threadIdx.x;
    if (i >= KM) return;
    int row = out_idx[i];
    int k = i / M_PTS;
    const unsigned* hw = hist + (size_t)row * 8;
    int w = k >> 2, r = k & 3;
    int pre = 0;
    for (int q = 0; q < w; ++q) pre += (int)bytesum(hw[q]);
    unsigned v = hw[w];
    for (int b = 0; b < r; ++b) pre += (int)((v >> (8 * b)) & 255u);
    unsigned old = atomicAdd(&cursor[(size_t)row * 8 + w], 1u << (8 * r));
    int inK = (int)((old >> (8 * r)) & 255u);
    int pos = partial[row] + blockOff[row >> 10] + pre + inK;
    entries[pos] = (k << 18) | in_idx[i];
}

// Prepack W, COALESCED layout [k][frag][lane]: slot (k,f,lane) holds the
// short8 whose element j = bf16(W[k][32s+8g+j][4c+tt]), f=s*4+tt, lane=(g,c).
// Consecutive lanes -> consecutive 16B (TA-friendly; was 128B-strided).
__global__ __launch_bounds__(64) void prepack_B(
    const float* __restrict__ W, unsigned short* __restrict__ packedB)
{
    const int k = blockIdx.x;
    const int lane = threadIdx.x;
    const int g = lane >> 4, c = lane & 15;
    const float* __restrict__ Wk = W + (size_t)k * C_CH * C_CH;
    #pragma unroll
    for (int s = 0; s < 2; ++s) {
        #pragma unroll
        for (int tt = 0; tt < 4; ++tt) {
            short8 v;
            #pragma unroll
            for (int j = 0; j < 8; ++j)
                v[j] = bf16c(Wk[(size_t)(32 * s + 8 * g + j) * C_CH + 4 * c + tt]);
            int f = s * 4 + tt;
            *(short8*)(packedB + ((size_t)(k * 8 + f) * 64 + lane) * 8) = v;
        }
    }
}

// ===========================================================================
// Output-stationary fused gather-GEMM. One wave = 1 tile of 16 rows.
// B-tile (8KB per k) cooperatively staged into LDS (double-buffered) —
// fragment reads are ds_read_b128, zero TA traffic. x16 swizzled layout
// gives each lane ONE contiguous 32B span per entry. Pipelines: ids depth-4,
// x depth-3 (static register shifts; refill from id3 — the NEW tail).
// ===========================================================================
__global__ __launch_bounds__(256, 4) void gather_bn_fused(
    const unsigned short* __restrict__ x16,
    const unsigned short* __restrict__ packedB,
    const int* __restrict__ entries, const int* __restrict__ partial,
    const int* __restrict__ blockOff,
    float* __restrict__ preact, float* __restrict__ pstats)
{
    __shared__ short8 bstage[2][512];   // [buf][f*64+lane], 16 KB
    __shared__ float shr[2][256][4];    // epilogue BN reduction, 8 KB

    const int tid = threadIdx.x;
    const int lane = tid & 63;
    const int wave = tid >> 6;
    const int g = lane >> 4, c = lane & 15;
    const int tile = blockIdx.x * 4 + wave;   // 0..24999
    const int row = tile * 16 + c;

    int ptr = partial[row] + blockOff[row >> 10];
    int end;
    if (row == N_OUT_PTS - 1) end = KM;
    else end = partial[row + 1] + blockOff[(row + 1) >> 10];

    // stage k=0 B-tile (coalesced: 256 threads x 2 consecutive short8)
    {
        const short8* sp = (const short8*)packedB;
        bstage[0][tid] = sp[tid];
        bstage[0][tid + 256] = sp[tid + 256];
    }

    // id pipeline depth 4; x pipeline depth 3. entries has a zeroed 64-int
    // pad past KM (max read ptr+3 <= KM+3), pad decodes to k=0/src=0 and is
    // never consumed (ptr >= end gates activity).
    int id0 = entries[ptr];
    int id1 = entries[ptr + 1];
    int id2 = entries[ptr + 2];
    int id3 = entries[ptr + 3];

    const unsigned short* __restrict__ xg = x16 + g * 16;  // lane slice base
    short8 xa0, xb0, xa1, xb1, xa2, xb2;
    {
        size_t s0 = (size_t)(id0 & SRC_MASK) * C_CH;
        xa0 = *(const short8*)(xg + s0); xb0 = *(const short8*)(xg + s0 + 8);
        size_t s1 = (size_t)(id1 & SRC_MASK) * C_CH;
        xa1 = *(const short8*)(xg + s1); xb1 = *(const short8*)(xg + s1 + 8);
        size_t s2 = (size_t)(id2 & SRC_MASK) * C_CH;
        xa2 = *(const short8*)(xg + s2); xb2 = *(const short8*)(xg + s2 + 8);
    }

    const short8 zero8 = {0, 0, 0, 0, 0, 0, 0, 0};
    f32x4 acc[4];
    #pragma unroll
    for (int tt = 0; tt < 4; ++tt) acc[tt] = (f32x4){0.f, 0.f, 0.f, 0.f};

    __syncthreads();   // k=0 staging visible
    int buf = 0;

    for (int k = 0; k < K_OFF; ++k) {
        // fragment regs from LDS (no TA)
        short8 bfrag[8];
        #pragma unroll
        for (int f = 0; f < 8; ++f) bfrag[f] = bstage[buf][f * 64 + lane];

        // issue next B-tile global loads (landed during the while-loop)
        short8 t0, t1;
        const bool stg = (k + 1 < K_OFF);
        if (stg) {
            const short8* sp = (const short8*)packedB + (size_t)(k + 1) * 512;
            t0 = sp[tid];
            t1 = sp[tid + 256];
        }

        while (__any(ptr < end && (id0 >> 18) == k)) {
            bool act = (ptr < end) && ((id0 >> 18) == k);
            short8 af0 = act ? xa0 : zero8;
            short8 af1 = act ? xb0 : zero8;
            if (act) {
                // advance pipelines. Refill source is id3: after the shift
                // below, old id3 becomes new id2, and xa2/xb2 must track it.
                // (Round-6 bug: refilled from old id2 -> duplicated row.)
                xa0 = xa1; xb0 = xb1;
                xa1 = xa2; xb1 = xb2;
                size_t s3 = (size_t)(id3 & SRC_MASK) * C_CH;
                xa2 = *(const short8*)(xg + s3);
                xb2 = *(const short8*)(xg + s3 + 8);
                id0 = id1; id1 = id2; id2 = id3;
                ++ptr;
                id3 = entries[ptr + 3];
            }
            #pragma unroll
            for (int tt = 0; tt < 4; ++tt) {
                f32x4 z = __builtin_amdgcn_mfma_f32_16x16x32_bf16(af0, bfrag[tt], acc[tt], 0, 0, 0);
                acc[tt] = __builtin_amdgcn_mfma_f32_16x16x32_bf16(af1, bfrag[4 + tt], z, 0, 0, 0);
            }
        }

        if (stg) {
            bstage[buf ^ 1][tid] = t0;          // other buffer: safe while
            bstage[buf ^ 1][tid + 256] = t1;    // peers still read buf
        }
        __syncthreads();
        buf ^= 1;
    }

    // Epilogue: coalesced preact writes + per-block BN partials (no atomics).
    float s[4] = {0.f, 0.f, 0.f, 0.f}, q[4] = {0.f, 0.f, 0.f, 0.f};
    #pragma unroll
    for (int e = 0; e < 4; ++e) {
        float4 w;
        w.x = acc[0][e]; w.y = acc[1][e]; w.z = acc[2][e]; w.w = acc[3][e];
        *(float4*)(preact + (size_t)(tile * 16 + 4 * g + e) * C_CH + 4 * c) = w;
        s[0] += w.x; s[1] += w.y; s[2] += w.z; s[3] += w.w;
        q[0] += w.x * w.x; q[1] += w.y * w.y; q[2] += w.z * w.z; q[3] += w.w * w.w;
    }

    #pragma unroll
    for (int tt = 0; tt < 4; ++tt) {
        shr[0][tid][tt] = s[tt];
        shr[1][tid][tt] = q[tt];
    }
    __syncthreads();
    if (tid < C_CH) {
        const int ch = tid;
        const int cc = ch >> 2, jj = ch & 3;
        float ts = 0.f, tq = 0.f;
        #pragma unroll
        for (int u = 0; u < 16; ++u) {
            ts += shr[0][16 * u + cc][jj];
            tq += shr[1][16 * u + cc][jj];
        }
        pstats[(size_t)blockIdx.x * 128 + ch] = ts;
        pstats[(size_t)blockIdx.x * 128 + C_CH + ch] = tq;
    }
}

// Reduce per-block BN partials: block b owns stats slot b (128 slots).
__global__ __launch_bounds__(256) void stats_reduce(
    const float* __restrict__ pstats, float* __restrict__ stats)
{
    const int b = blockIdx.x;   // 0..127
    float s = 0.f;
    for (int i = threadIdx.x; i < GBLOCKS; i += 256)
        s += pstats[(size_t)i * 128 + b];
    __shared__ float sh[256];
    sh[threadIdx.x] = s;
    __syncthreads();
    for (int o = 128; o > 0; o >>= 1) {
        if (threadIdx.x < o) sh[threadIdx.x] += sh[threadIdx.x + o];
        __syncthreads();
    }
    if (threadIdx.x == 0) stats[b] = sh[0];
}

// In-place BN+ReLU on fp32 preact (= d_out).
__global__ __launch_bounds__(256) void bn_apply_f32(
    float* __restrict__ out, const float* __restrict__ stats,
    const float* __restrict__ gamma, const float* __restrict__ beta)
{
    const float inv_n = 1.0f / (float)N_OUT_PTS;
    const int c0 = 8 * (threadIdx.x & 7);
    float sc[8], bs[8];
    #pragma unroll
    for (int j = 0; j < 8; ++j) {
        int ch = c0 + j;
        float mean = stats[ch] * inv_n;
        float var = stats[C_CH + ch] * inv_n - mean * mean;
        float sfac = gamma[ch] * rsqrtf(var + BN_EPS);
        sc[j] = sfac;
        bs[j] = beta[ch] - mean * sfac;
    }
    float4* o4 = (float4*)out;
    const size_t n = (size_t)N_OUT_PTS * C_CH / 8;
    const size_t stride = (size_t)gridDim.x * blockDim.x;
    for (size_t i = (size_t)blockIdx.x * blockDim.x + threadIdx.x; i < n; i += stride) {
        float4 r0 = o4[2 * i], r1 = o4[2 * i + 1];
        r0.x = fmaxf(fmaf(r0.x, sc[0], bs[0]), 0.f);
        r0.y = fmaxf(fmaf(r0.y, sc[1], bs[1]), 0.f);
        r0.z = fmaxf(fmaf(r0.z, sc[2], bs[2]), 0.f);
        r0.w = fmaxf(fmaf(r0.w, sc[3], bs[3]), 0.f);
        r1.x = fmaxf(fmaf(r1.x, sc[4], bs[4]), 0.f);
        r1.y = fmaxf(fmaf(r1.y, sc[5], bs[5]), 0.f);
        r1.z = fmaxf(fmaf(r1.z, sc[6], bs[6]), 0.f);
        r1.w = fmaxf(fmaf(r1.w, sc[7], bs[7]), 0.f);
        o4[2 * i] = r0;
        o4[2 * i + 1] = r1;
    }
}

// ===========================================================================
// FALLBACK (ws implausibly small): atomic-scatter pipeline, proven pass.
// ===========================================================================
#define TILE_PTS 16
#define NT (M_PTS / TILE_PTS)
#define FB_BLKX 64
#define FB_WSTRIDE (FB_BLKX * 4)

__global__ __launch_bounds__(256, 4) void scatter_gemm_fb(
    const float* __restrict__ x, const float* __restrict__ W,
    const int* __restrict__ in_idx, const int* __restrict__ out_idx,
    __hip_bfloat16* __restrict__ out_ws)
{
    const int k = blockIdx.y;
    const int lane = threadIdx.x & 63;
    const int wave = threadIdx.x >> 6;
    const int g = lane >> 4, c = lane & 15;
    short8 bfrag[2][4];
    {
        const float* __restrict__ Wk = W + (size_t)k * C_CH * C_CH;
        #pragma unroll
        for (int s = 0; s < 2; ++s)
            #pragma unroll
            for (int tt = 0; tt < 4; ++tt) {
                short8 v;
                #pragma unroll
                for (int j = 0; j < 8; ++j)
                    v[j] = bf16c(Wk[(size_t)(32 * s + 8 * g + j) * C_CH + 4 * c + tt]);
                bfrag[s][tt] = v;
            }
    }
    const int kbase = k * M_PTS;
    for (int t = blockIdx.x * 4 + wave; t < NT; t += FB_WSTRIDE) {
        int src = in_idx[kbase + t * TILE_PTS + c];
        const float4* xr = (const float4*)x + (size_t)src * 16;
        float4 cur[4];
        cur[0] = xr[2 * g];     cur[1] = xr[2 * g + 1];
        cur[2] = xr[8 + 2 * g]; cur[3] = xr[8 + 2 * g + 1];
        int dstv[4];
        #pragma unroll
        for (int e = 0; e < 4; ++e)
            dstv[e] = out_idx[kbase + t * TILE_PTS + 4 * g + e];
        short8 af0, af1;
        #pragma unroll
        for (int j = 0; j < 4; ++j) {
            af0[j] = bf16c(cur[0][j]); af0[j + 4] = bf16c(cur[1][j]);
            af1[j] = bf16c(cur[2][j]); af1[j + 4] = bf16c(cur[3][j]);
        }
        f32x4 acc[4];
        #pragma unroll
        for (int tt = 0; tt < 4; ++tt) {
            f32x4 z = {0.f, 0.f, 0.f, 0.f};
            z       = __builtin_amdgcn_mfma_f32_16x16x32_bf16(af0, bfrag[0][tt], z, 0, 0, 0);
            acc[tt] = __builtin_amdgcn_mfma_f32_16x16x32_bf16(af1, bfrag[1][tt], z, 0, 0, 0);
        }
        #pragma unroll
        for (int e = 0; e < 4; ++e) {
            __hip_bfloat16* rp = out_ws + (size_t)dstv[e] * C_CH + 4 * c;
            union { __hip_bfloat162 h; int i; } p0, p1;
            p0.h = __hip_bfloat162(__float2bfloat16(acc[0][e]), __float2bfloat16(acc[1][e]));
            p1.h = __hip_bfloat162(__float2bfloat16(acc[2][e]), __float2bfloat16(acc[3][e]));
            pk_atomic_add_bf16(rp, p0.i);
            pk_atomic_add_bf16(rp + 2, p1.i);
        }
    }
}

__global__ __launch_bounds__(256) void bn_stats_fb(
    const __hip_bfloat16* __restrict__ ws, float* __restrict__ stats)
{
    const uint4* in = (const uint4*)ws;
    const size_t n = (size_t)N_OUT_PTS * C_CH / 8;
    const size_t stride = (size_t)gridDim.x * blockDim.x;
    float s[8], s2[8];
    #pragma unroll
    for (int j = 0; j < 8; ++j) { s[j] = 0.f; s2[j] = 0.f; }
    for (size_t i = (size_t)blockIdx.x * blockDim.x + threadIdx.x; i < n; i += stride) {
        uint4 qv = in[i];
        unsigned wds[4] = {qv.x, qv.y, qv.z, qv.w};
        #pragma unroll
        for (int j = 0; j < 4; ++j) {
            __hip_bfloat162 h = *(__hip_bfloat162*)&wds[j];
            float f0 = __low2float(h), f1 = __high2float(h);
            s[2 * j] += f0;  s2[2 * j] += f0 * f0;
            s[2 * j + 1] += f1; s2[2 * j + 1] += f1 * f1;
        }
    }
    __shared__ float sh[2][256][8];
    #pragma unroll
    for (int j = 0; j < 8; ++j) { sh[0][threadIdx.x][j] = s[j]; sh[1][threadIdx.x][j] = s2[j]; }
    __syncthreads();
    if (threadIdx.x < C_CH) {
        const int cch = threadIdx.x;
        float ts = 0.f, t2 = 0.f;
        #pragma unroll
        for (int u = 0; u < 32; ++u) {
            ts += sh[0][8 * u + (cch >> 3)][cch & 7];
            t2 += sh[1][8 * u + (cch >> 3)][cch & 7];
        }
        unsafeAtomicAdd(&stats[cch], ts);
        unsafeAtomicAdd(&stats[C_CH + cch], t2);
    }
}

__global__ __launch_bounds__(256) void bn_apply_fb(
    const __hip_bfloat16* __restrict__ ws, const float* __restrict__ stats,
    const float* __restrict__ gamma, const float* __restrict__ beta,
    float* __restrict__ out)
{
    const float inv_n = 1.0f / (float)N_OUT_PTS;
    const int c0 = 8 * (threadIdx.x & 7);
    float sc[8], bs[8];
    #pragma unroll
    for (int j = 0; j < 8; ++j) {
        int ch = c0 + j;
        float mean = stats[ch] * inv_n;
        float var = stats[C_CH + ch] * inv_n - mean * mean;
        float sfac = gamma[ch] * rsqrtf(var + BN_EPS);
        sc[j] = sfac;
        bs[j] = beta[ch] - mean * sfac;
    }
    const uint4* in = (const uint4*)ws;
    float4* o4 = (float4*)out;
    const size_t n = (size_t)N_OUT_PTS * C_CH / 8;
    const size_t stride = (size_t)gridDim.x * blockDim.x;
    for (size_t i = (size_t)blockIdx.x * blockDim.x + threadIdx.x; i < n; i += stride) {
        uint4 qv = in[i];
        unsigned wds[4] = {qv.x, qv.y, qv.z, qv.w};
        float f[8];
        #pragma unroll
        for (int j = 0; j < 4; ++j) {
            __hip_bfloat162 h = *(__hip_bfloat162*)&wds[j];
            f[2 * j] = __low2float(h);
            f[2 * j + 1] = __high2float(h);
        }
        float4 r0, r1;
        r0.x = fmaxf(fmaf(f[0], sc[0], bs[0]), 0.f);
        r0.y = fmaxf(fmaf(f[1], sc[1], bs[1]), 0.f);
        r0.z = fmaxf(fmaf(f[2], sc[2], bs[2]), 0.f);
        r0.w = fmaxf(fmaf(f[3], sc[3], bs[3]), 0.f);
        r1.x = fmaxf(fmaf(f[4], sc[4], bs[4]), 0.f);
        r1.y = fmaxf(fmaf(f[5], sc[5], bs[5]), 0.f);
        r1.z = fmaxf(fmaf(f[6], sc[6], bs[6]), 0.f);
        r1.w = fmaxf(fmaf(f[7], sc[7], bs[7]), 0.f);
        o4[2 * i] = r0;
        o4[2 * i + 1] = r1;
    }
}

extern "C" void kernel_launch(void* const* d_in, const int* in_sizes, int n_in,
                              void* d_out, int out_size, void* d_ws, size_t ws_size,
                              hipStream_t stream) {
    const float* x      = (const float*)d_in[0];
    const float* W      = (const float*)d_in[1];
    const float* gamma  = (const float*)d_in[2];
    const float* beta   = (const float*)d_in[3];
    const int*   in_idx = (const int*)d_in[4];
    const int*   out_idx= (const int*)d_in[5];
    float* out = (float*)d_out;

    // Workspace layout (~42 MB). hist+cursor (25.6 MB) are DEAD after
    // fill_kernel and are reused as the swizzled bf16 x copy (xconv).
    auto al = [](size_t v) { return (v + 255) & ~(size_t)255; };
    size_t off = 0;
    const size_t entries_off = off; off += al((size_t)(KM + 64) * 4);
    const size_t partial_off = off; off += al((size_t)N_OUT_PTS * 4);
    const size_t zero_start  = off;
    const size_t hist_off    = off; off += al((size_t)N_OUT_PTS * 32);
    const size_t cursor_off  = off; off += al((size_t)N_OUT_PTS * 32);
    const size_t bsum_off    = off; off += al(512 * 4);
    const size_t boff_off    = off; off += al(512 * 4);
    const size_t stats_off   = off; off += al(2 * C_CH * sizeof(float));
    const size_t zero_end    = off;
    const size_t pstats_off  = off; off += al((size_t)GBLOCKS * 128 * 4);
    const size_t packB_off   = off; off += al((size_t)K_OFF * 64 * 128);
    const size_t NEEDED = off;

    if (ws_size >= NEEDED) {
        char* wsb = (char*)d_ws;
        int*      entries = (int*)(wsb + entries_off);
        int*      partial = (int*)(wsb + partial_off);
        unsigned* hist    = (unsigned*)(wsb + hist_off);
        unsigned* cursor  = (unsigned*)(wsb + cursor_off);
        int*      bsum    = (int*)(wsb + bsum_off);
        int*      boff    = (int*)(wsb + boff_off);
        float*    stats   = (float*)(wsb + stats_off);
        float*    pstats  = (float*)(wsb + pstats_off);
        unsigned short* packB = (unsigned short*)(wsb + packB_off);
        unsigned short* x16   = (unsigned short*)(wsb + hist_off);  // reuse

        (void)hipMemsetAsync(wsb + zero_start, 0, zero_end - zero_start, stream);
        (void)hipMemsetAsync(entries + KM, 0, 64 * sizeof(int), stream);

        prepack_B<<<K_OFF, 64, 0, stream>>>(W, packB);
        hist_kernel<<<(KM + 255) / 256, 256, 0, stream>>>(out_idx, hist);
        scan_a<<<SCAN_BLOCKS, 256, 0, stream>>>(hist, partial, bsum);
        scan_b<<<1, 512, 0, stream>>>(bsum, boff);
        fill_kernel<<<(KM + 255) / 256, 256, 0, stream>>>(
            out_idx, in_idx, hist, cursor, partial, boff, entries);
        xconv<<<(200000 * 4 + 255) / 256, 256, 0, stream>>>(x, x16);
        gather_bn_fused<<<GBLOCKS, 256, 0, stream>>>(
            x16, packB, entries, partial, boff, out, pstats);
        stats_reduce<<<128, 256, 0, stream>>>(pstats, stats);
        bn_apply_f32<<<2048, 256, 0, stream>>>(out, stats, gamma, beta);
    } else {
        __hip_bfloat16* out_ws = (__hip_bfloat16*)d_ws;
        const size_t acc_elems = (size_t)N_OUT_PTS * C_CH;
        float* stats = (float*)((char*)d_ws + acc_elems * sizeof(__hip_bfloat16));
        const size_t clear_bytes = acc_elems * sizeof(__hip_bfloat16) + 2 * C_CH * sizeof(float);
        (void)hipMemsetAsync(d_ws, 0, clear_bytes, stream);
        scatter_gemm_fb<<<dim3(FB_BLKX, K_OFF), 256, 0, stream>>>(x, W, in_idx, out_idx, out_ws);
        bn_stats_fb<<<2048, 256, 0, stream>>>(out_ws, stats);
        bn_apply_fb<<<2048, 256, 0, stream>>>(out_ws, stats, gamma, beta, out);
    }
}

// Round 8
// 760.810 us; speedup vs baseline: 1.8117x; 1.8117x over previous
//
#include <hip/hip_runtime.h>
#include <hip/hip_bf16.h>

// Problem constants (fixed by the reference file).
#define K_OFF 27
#define M_PTS 100000
#define KM (K_OFF * M_PTS)      // 2,700,000 contributions
#define C_CH 64
#define N_OUT_PTS 400000
#define BN_EPS 1e-5f
#define N_TILES (N_OUT_PTS / 16)   // 25000 output tiles of 16 rows
#define GBLOCKS (N_TILES / 4)      // 6250 gather blocks: 4 waves, 1 tile/wave
#define SRC_MASK 0x3FFFF           // entries pack (k<<18)|src, src<200000<2^18

typedef __attribute__((ext_vector_type(8))) short short8;  // 8 bf16 = 4 VGPRs
typedef __attribute__((ext_vector_type(4))) float f32x4;

__device__ inline short bf16c(float f) {
    return __builtin_bit_cast(short, __float2bfloat16(f));
}

// Packed 2xbf16 atomic add (fallback path only).
__device__ inline void pk_atomic_add_bf16(__hip_bfloat16* p, int bits) {
#if __has_builtin(__builtin_amdgcn_global_atomic_fadd_v2bf16)
    typedef short s2v __attribute__((ext_vector_type(2)));
    typedef __attribute__((address_space(1))) s2v* gp;
    s2v v;
    __builtin_memcpy(&v, &bits, 4);
    __builtin_amdgcn_global_atomic_fadd_v2bf16((gp)(unsigned long long)p, v);
#else
    asm volatile("global_atomic_pk_add_bf16 %0, %1, off"
                 :: "v"((unsigned long long)p), "v"(bits) : "memory");
#endif
}

__device__ inline unsigned bytesum(unsigned v) {
    return (v & 255u) + ((v >> 8) & 255u) + ((v >> 16) & 255u) + (v >> 24);
}

// ===========================================================================
// x fp32 -> bf16, SWIZZLED per row so lane g's per-entry 32B is contiguous:
// x16[row*64 + g*16 + 0..7]  = cin[8g .. 8g+7]       (af0 slice)
// x16[row*64 + g*16 + 8..15] = cin[32+8g .. 32+8g+7] (af1 slice)
// ===========================================================================
__global__ __launch_bounds__(256) void xconv(
    const float* __restrict__ x, unsigned short* __restrict__ x16)
{
    int t = blockIdx.x * 256 + threadIdx.x;   // (row, g); 800000 total
    if (t >= 200000 * 4) return;
    int row = t >> 2, g = t & 3;
    const float* __restrict__ in = x + (size_t)row * C_CH;
    short8 v0, v1;
    #pragma unroll
    for (int j = 0; j < 8; ++j) {
        v0[j] = bf16c(in[8 * g + j]);
        v1[j] = bf16c(in[32 + 8 * g + j]);
    }
    unsigned short* o = x16 + (size_t)row * C_CH + g * 16;
    *(short8*)o = v0;
    *(short8*)(o + 8) = v1;
}

// ===========================================================================
// CSR construction: per-(row,k) byte-packed histogram -> scan -> k-sorted fill
// ===========================================================================

__global__ __launch_bounds__(256) void hist_kernel(
    const int* __restrict__ out_idx, unsigned* __restrict__ hist)
{
    int i = blockIdx.x * 256 + threadIdx.x;
    if (i >= KM) return;
    int row = out_idx[i];
    int k = i / M_PTS;
    atomicAdd(&hist[(size_t)row * 8 + (k >> 2)], 1u << (8 * (k & 3)));
}

__global__ __launch_bounds__(256) void scan_a(
    const unsigned* __restrict__ hist, int* __restrict__ partial,
    int* __restrict__ blockSums)
{
    __shared__ int sh[256];
    const int t = threadIdx.x, b = blockIdx.x;
    const int r0 = b * 1024 + t * 4;
    int cnt[4] = {0, 0, 0, 0};
    if (r0 < N_OUT_PTS) {
        #pragma unroll
        for (int u = 0; u < 4; ++u) {
            const uint4* hp = (const uint4*)(hist + (size_t)(r0 + u) * 8);
            uint4 a = hp[0], bq = hp[1];
            cnt[u] = (int)(bytesum(a.x) + bytesum(a.y) + bytesum(a.z) + bytesum(a.w) +
                           bytesum(bq.x) + bytesum(bq.y) + bytesum(bq.z) + bytesum(bq.w));
        }
    }
    int tsum = cnt[0] + cnt[1] + cnt[2] + cnt[3];
    sh[t] = tsum;
    __syncthreads();
    for (int o = 1; o < 256; o <<= 1) {
        int u = (t >= o) ? sh[t - o] : 0;
        __syncthreads();
        sh[t] += u;
        __syncthreads();
    }
    int excl = sh[t] - tsum;
    if (r0 < N_OUT_PTS) {
        partial[r0]     = excl;
        partial[r0 + 1] = excl + cnt[0];
        partial[r0 + 2] = excl + cnt[0] + cnt[1];
        partial[r0 + 3] = excl + cnt[0] + cnt[1] + cnt[2];
    }
    if (t == 255) blockSums[b] = sh[255];
}

#define SCAN_BLOCKS ((N_OUT_PTS + 1023) / 1024)   // 391

__global__ __launch_bounds__(512) void scan_b(
    const int* __restrict__ blockSums, int* __restrict__ blockOff)
{
    __shared__ int sh[512];
    const int t = threadIdx.x;
    int v = (t < SCAN_BLOCKS) ? blockSums[t] : 0;
    sh[t] = v;
    __syncthreads();
    for (int o = 1; o < 512; o <<= 1) {
        int u = (t >= o) ? sh[t - o] : 0;
        __syncthreads();
        sh[t] += u;
        __syncthreads();
    }
    if (t < SCAN_BLOCKS) blockOff[t] = sh[t] - v;
}

__global__ __launch_bounds__(256) void fill_kernel(
    const int* __restrict__ out_idx, const int* __restrict__ in_idx,
    const unsigned* __restrict__ hist, unsigned* __restrict__ cursor,
    const int* __restrict__ partial, const int* __restrict__ blockOff,
    int* __restrict__ entries)
{
    int i = blockIdx.x * 256 + threadIdx.x;
    if (i >= KM) return;
    int row = out_idx[i];
    int k = i / M_PTS;
    const unsigned* hw = hist + (size_t)row * 8;
    int w = k >> 2, r = k & 3;
    int pre = 0;
    for (int q = 0; q < w; ++q) pre += (int)bytesum(hw[q]);
    unsigned v = hw[w];
    for (int b = 0; b < r; ++b) pre += (int)((v >> (8 * b)) & 255u);
    unsigned old = atomicAdd(&cursor[(size_t)row * 8 + w], 1u << (8 * r));
    int inK = (int)((old >> (8 * r)) & 255u);
    int pos = partial[row] + blockOff[row >> 10] + pre + inK;
    entries[pos] = (k << 18) | in_idx[i];
}

// Prepack W, COALESCED layout [k][frag][lane]: slot (k,f,lane) holds the
// short8 whose element j = bf16(W[k][32s+8g+j][4c+tt]), f=s*4+tt, lane=(g,c).
// A bfrag load has 64 lanes reading ONE contiguous 1KB block (1 line set),
// vs the old [k][lane][frag] layout where every load touched 64 lines.
__global__ __launch_bounds__(64) void prepack_B(
    const float* __restrict__ W, unsigned short* __restrict__ packedB)
{
    const int k = blockIdx.x;
    const int lane = threadIdx.x;
    const int g = lane >> 4, c = lane & 15;
    const float* __restrict__ Wk = W + (size_t)k * C_CH * C_CH;
    #pragma unroll
    for (int s = 0; s < 2; ++s) {
        #pragma unroll
        for (int tt = 0; tt < 4; ++tt) {
            short8 v;
            #pragma unroll
            for (int j = 0; j < 8; ++j)
                v[j] = bf16c(Wk[(size_t)(32 * s + 8 * g + j) * C_CH + 4 * c + tt]);
            int f = s * 4 + tt;
            *(short8*)(packedB + ((size_t)(k * 8 + f) * 64 + lane) * 8) = v;
        }
    }
}

// ===========================================================================
// Output-stationary fused gather-GEMM. One wave = 1 tile of 16 rows.
// ROUND-5-PROVEN loop structure (x-pipe depth 2, ids depth 3, no barriers,
// no LDS staging, no registers held across the while-loop beyond the pipe) —
// the ONLY change vs round 5 is the coalesced packedB layout. Round 7's
// LDS-B variant spilled (WRITE_SIZE 103MB -> 1.73GB scratch); reverted.
// ===========================================================================
__global__ __launch_bounds__(256, 4) void gather_bn_fused(
    const unsigned short* __restrict__ x16,
    const unsigned short* __restrict__ packedB,
    const int* __restrict__ entries, const int* __restrict__ partial,
    const int* __restrict__ blockOff,
    float* __restrict__ preact, float* __restrict__ pstats)
{
    const int tid = threadIdx.x;
    const int lane = tid & 63;
    const int wave = tid >> 6;
    const int g = lane >> 4, c = lane & 15;
    const int tile = blockIdx.x * 4 + wave;   // 0..24999
    const int row = tile * 16 + c;

    int ptr = partial[row] + blockOff[row >> 10];
    int end;
    if (row == N_OUT_PTS - 1) end = KM;
    else end = partial[row + 1] + blockOff[(row + 1) >> 10];

    // id pipeline depth 3; x pipeline depth 2. entries has a zeroed 64-int
    // pad past KM (max read ptr+2 <= KM+2), pad decodes to k=0/src=0 and is
    // never consumed (ptr >= end gates activity).
    int id0 = entries[ptr];
    int id1 = entries[ptr + 1];
    int id2 = entries[ptr + 2];

    const unsigned short* __restrict__ xg = x16 + g * 16;  // lane slice base
    short8 xa0, xb0, xa1, xb1;
    {
        size_t s0 = (size_t)(id0 & SRC_MASK) * C_CH;
        xa0 = *(const short8*)(xg + s0); xb0 = *(const short8*)(xg + s0 + 8);
        size_t s1 = (size_t)(id1 & SRC_MASK) * C_CH;
        xa1 = *(const short8*)(xg + s1); xb1 = *(const short8*)(xg + s1 + 8);
    }

    const short8 zero8 = {0, 0, 0, 0, 0, 0, 0, 0};
    f32x4 acc[4];
    #pragma unroll
    for (int tt = 0; tt < 4; ++tt) acc[tt] = (f32x4){0.f, 0.f, 0.f, 0.f};

    for (int k = 0; k < K_OFF; ++k) {
        // 8 coalesced bfrag loads (each: 64 lanes x 16B = one 1KB block)
        short8 bfrag[8];
        {
            const short8* bp = (const short8*)packedB + (size_t)k * 512;
            #pragma unroll
            for (int f = 0; f < 8; ++f) bfrag[f] = bp[f * 64 + lane];
        }

        while (__any(ptr < end && (id0 >> 18) == k)) {
            bool act = (ptr < end) && ((id0 >> 18) == k);
            short8 af0 = act ? xa0 : zero8;
            short8 af1 = act ? xb0 : zero8;
            if (act) {
                // depth-2 advance (round-5-proven): refill from OLD id2,
                // which becomes NEW id1 after the shift -> xa1 tracks id1.
                xa0 = xa1; xb0 = xb1;
                size_t s2 = (size_t)(id2 & SRC_MASK) * C_CH;
                xa1 = *(const short8*)(xg + s2);
                xb1 = *(const short8*)(xg + s2 + 8);
                id0 = id1; id1 = id2;
                ++ptr;
                id2 = entries[ptr + 2];
            }
            #pragma unroll
            for (int tt = 0; tt < 4; ++tt) {
                f32x4 z = __builtin_amdgcn_mfma_f32_16x16x32_bf16(af0, bfrag[tt], acc[tt], 0, 0, 0);
                acc[tt] = __builtin_amdgcn_mfma_f32_16x16x32_bf16(af1, bfrag[4 + tt], z, 0, 0, 0);
            }
        }
    }

    // Epilogue: coalesced preact writes + per-block BN partials (no atomics).
    float s[4] = {0.f, 0.f, 0.f, 0.f}, q[4] = {0.f, 0.f, 0.f, 0.f};
    #pragma unroll
    for (int e = 0; e < 4; ++e) {
        float4 w;
        w.x = acc[0][e]; w.y = acc[1][e]; w.z = acc[2][e]; w.w = acc[3][e];
        *(float4*)(preact + (size_t)(tile * 16 + 4 * g + e) * C_CH + 4 * c) = w;
        s[0] += w.x; s[1] += w.y; s[2] += w.z; s[3] += w.w;
        q[0] += w.x * w.x; q[1] += w.y * w.y; q[2] += w.z * w.z; q[3] += w.w * w.w;
    }

    __shared__ float shr[2][256][4];
    #pragma unroll
    for (int tt = 0; tt < 4; ++tt) {
        shr[0][tid][tt] = s[tt];
        shr[1][tid][tt] = q[tt];
    }
    __syncthreads();
    if (tid < C_CH) {
        const int ch = tid;
        const int cc = ch >> 2, jj = ch & 3;
        float ts = 0.f, tq = 0.f;
        #pragma unroll
        for (int u = 0; u < 16; ++u) {
            ts += shr[0][16 * u + cc][jj];
            tq += shr[1][16 * u + cc][jj];
        }
        pstats[(size_t)blockIdx.x * 128 + ch] = ts;
        pstats[(size_t)blockIdx.x * 128 + C_CH + ch] = tq;
    }
}

// Reduce per-block BN partials: block b owns stats slot b (128 slots).
__global__ __launch_bounds__(256) void stats_reduce(
    const float* __restrict__ pstats, float* __restrict__ stats)
{
    const int b = blockIdx.x;   // 0..127
    float s = 0.f;
    for (int i = threadIdx.x; i < GBLOCKS; i += 256)
        s += pstats[(size_t)i * 128 + b];
    __shared__ float sh[256];
    sh[threadIdx.x] = s;
    __syncthreads();
    for (int o = 128; o > 0; o >>= 1) {
        if (threadIdx.x < o) sh[threadIdx.x] += sh[threadIdx.x + o];
        __syncthreads();
    }
    if (threadIdx.x == 0) stats[b] = sh[0];
}

// In-place BN+ReLU on fp32 preact (= d_out).
__global__ __launch_bounds__(256) void bn_apply_f32(
    float* __restrict__ out, const float* __restrict__ stats,
    const float* __restrict__ gamma, const float* __restrict__ beta)
{
    const float inv_n = 1.0f / (float)N_OUT_PTS;
    const int c0 = 8 * (threadIdx.x & 7);
    float sc[8], bs[8];
    #pragma unroll
    for (int j = 0; j < 8; ++j) {
        int ch = c0 + j;
        float mean = stats[ch] * inv_n;
        float var = stats[C_CH + ch] * inv_n - mean * mean;
        float sfac = gamma[ch] * rsqrtf(var + BN_EPS);
        sc[j] = sfac;
        bs[j] = beta[ch] - mean * sfac;
    }
    float4* o4 = (float4*)out;
    const size_t n = (size_t)N_OUT_PTS * C_CH / 8;
    const size_t stride = (size_t)gridDim.x * blockDim.x;
    for (size_t i = (size_t)blockIdx.x * blockDim.x + threadIdx.x; i < n; i += stride) {
        float4 r0 = o4[2 * i], r1 = o4[2 * i + 1];
        r0.x = fmaxf(fmaf(r0.x, sc[0], bs[0]), 0.f);
        r0.y = fmaxf(fmaf(r0.y, sc[1], bs[1]), 0.f);
        r0.z = fmaxf(fmaf(r0.z, sc[2], bs[2]), 0.f);
        r0.w = fmaxf(fmaf(r0.w, sc[3], bs[3]), 0.f);
        r1.x = fmaxf(fmaf(r1.x, sc[4], bs[4]), 0.f);
        r1.y = fmaxf(fmaf(r1.y, sc[5], bs[5]), 0.f);
        r1.z = fmaxf(fmaf(r1.z, sc[6], bs[6]), 0.f);
        r1.w = fmaxf(fmaf(r1.w, sc[7], bs[7]), 0.f);
        o4[2 * i] = r0;
        o4[2 * i + 1] = r1;
    }
}

// ===========================================================================
// FALLBACK (ws implausibly small): atomic-scatter pipeline, proven pass.
// ===========================================================================
#define TILE_PTS 16
#define NT (M_PTS / TILE_PTS)
#define FB_BLKX 64
#define FB_WSTRIDE (FB_BLKX * 4)

__global__ __launch_bounds__(256, 4) void scatter_gemm_fb(
    const float* __restrict__ x, const float* __restrict__ W,
    const int* __restrict__ in_idx, const int* __restrict__ out_idx,
    __hip_bfloat16* __restrict__ out_ws)
{
    const int k = blockIdx.y;
    const int lane = threadIdx.x & 63;
    const int wave = threadIdx.x >> 6;
    const int g = lane >> 4, c = lane & 15;
    short8 bfrag[2][4];
    {
        const float* __restrict__ Wk = W + (size_t)k * C_CH * C_CH;
        #pragma unroll
        for (int s = 0; s < 2; ++s)
            #pragma unroll
            for (int tt = 0; tt < 4; ++tt) {
                short8 v;
                #pragma unroll
                for (int j = 0; j < 8; ++j)
                    v[j] = bf16c(Wk[(size_t)(32 * s + 8 * g + j) * C_CH + 4 * c + tt]);
                bfrag[s][tt] = v;
            }
    }
    const int kbase = k * M_PTS;
    for (int t = blockIdx.x * 4 + wave; t < NT; t += FB_WSTRIDE) {
        int src = in_idx[kbase + t * TILE_PTS + c];
        const float4* xr = (const float4*)x + (size_t)src * 16;
        float4 cur[4];
        cur[0] = xr[2 * g];     cur[1] = xr[2 * g + 1];
        cur[2] = xr[8 + 2 * g]; cur[3] = xr[8 + 2 * g + 1];
        int dstv[4];
        #pragma unroll
        for (int e = 0; e < 4; ++e)
            dstv[e] = out_idx[kbase + t * TILE_PTS + 4 * g + e];
        short8 af0, af1;
        #pragma unroll
        for (int j = 0; j < 4; ++j) {
            af0[j] = bf16c(cur[0][j]); af0[j + 4] = bf16c(cur[1][j]);
            af1[j] = bf16c(cur[2][j]); af1[j + 4] = bf16c(cur[3][j]);
        }
        f32x4 acc[4];
        #pragma unroll
        for (int tt = 0; tt < 4; ++tt) {
            f32x4 z = {0.f, 0.f, 0.f, 0.f};
            z       = __builtin_amdgcn_mfma_f32_16x16x32_bf16(af0, bfrag[0][tt], z, 0, 0, 0);
            acc[tt] = __builtin_amdgcn_mfma_f32_16x16x32_bf16(af1, bfrag[1][tt], z, 0, 0, 0);
        }
        #pragma unroll
        for (int e = 0; e < 4; ++e) {
            __hip_bfloat16* rp = out_ws + (size_t)dstv[e] * C_CH + 4 * c;
            union { __hip_bfloat162 h; int i; } p0, p1;
            p0.h = __hip_bfloat162(__float2bfloat16(acc[0][e]), __float2bfloat16(acc[1][e]));
            p1.h = __hip_bfloat162(__float2bfloat16(acc[2][e]), __float2bfloat16(acc[3][e]));
            pk_atomic_add_bf16(rp, p0.i);
            pk_atomic_add_bf16(rp + 2, p1.i);
        }
    }
}

__global__ __launch_bounds__(256) void bn_stats_fb(
    const __hip_bfloat16* __restrict__ ws, float* __restrict__ stats)
{
    const uint4* in = (const uint4*)ws;
    const size_t n = (size_t)N_OUT_PTS * C_CH / 8;
    const size_t stride = (size_t)gridDim.x * blockDim.x;
    float s[8], s2[8];
    #pragma unroll
    for (int j = 0; j < 8; ++j) { s[j] = 0.f; s2[j] = 0.f; }
    for (size_t i = (size_t)blockIdx.x * blockDim.x + threadIdx.x; i < n; i += stride) {
        uint4 qv = in[i];
        unsigned wds[4] = {qv.x, qv.y, qv.z, qv.w};
        #pragma unroll
        for (int j = 0; j < 4; ++j) {
            __hip_bfloat162 h = *(__hip_bfloat162*)&wds[j];
            float f0 = __low2float(h), f1 = __high2float(h);
            s[2 * j] += f0;  s2[2 * j] += f0 * f0;
            s[2 * j + 1] += f1; s2[2 * j + 1] += f1 * f1;
        }
    }
    __shared__ float sh[2][256][8];
    #pragma unroll
    for (int j = 0; j < 8; ++j) { sh[0][threadIdx.x][j] = s[j]; sh[1][threadIdx.x][j] = s2[j]; }
    __syncthreads();
    if (threadIdx.x < C_CH) {
        const int cch = threadIdx.x;
        float ts = 0.f, t2 = 0.f;
        #pragma unroll
        for (int u = 0; u < 32; ++u) {
            ts += sh[0][8 * u + (cch >> 3)][cch & 7];
            t2 += sh[1][8 * u + (cch >> 3)][cch & 7];
        }
        unsafeAtomicAdd(&stats[cch], ts);
        unsafeAtomicAdd(&stats[C_CH + cch], t2);
    }
}

__global__ __launch_bounds__(256) void bn_apply_fb(
    const __hip_bfloat16* __restrict__ ws, const float* __restrict__ stats,
    const float* __restrict__ gamma, const float* __restrict__ beta,
    float* __restrict__ out)
{
    const float inv_n = 1.0f / (float)N_OUT_PTS;
    const int c0 = 8 * (threadIdx.x & 7);
    float sc[8], bs[8];
    #pragma unroll
    for (int j = 0; j < 8; ++j) {
        int ch = c0 + j;
        float mean = stats[ch] * inv_n;
        float var = stats[C_CH + ch] * inv_n - mean * mean;
        float sfac = gamma[ch] * rsqrtf(var + BN_EPS);
        sc[j] = sfac;
        bs[j] = beta[ch] - mean * sfac;
    }
    const uint4* in = (const uint4*)ws;
    float4* o4 = (float4*)out;
    const size_t n = (size_t)N_OUT_PTS * C_CH / 8;
    const size_t stride = (size_t)gridDim.x * blockDim.x;
    for (size_t i = (size_t)blockIdx.x * blockDim.x + threadIdx.x; i < n; i += stride) {
        uint4 qv = in[i];
        unsigned wds[4] = {qv.x, qv.y, qv.z, qv.w};
        float f[8];
        #pragma unroll
        for (int j = 0; j < 4; ++j) {
            __hip_bfloat162 h = *(__hip_bfloat162*)&wds[j];
            f[2 * j] = __low2float(h);
            f[2 * j + 1] = __high2float(h);
        }
        float4 r0, r1;
        r0.x = fmaxf(fmaf(f[0], sc[0], bs[0]), 0.f);
        r0.y = fmaxf(fmaf(f[1], sc[1], bs[1]), 0.f);
        r0.z = fmaxf(fmaf(f[2], sc[2], bs[2]), 0.f);
        r0.w = fmaxf(fmaf(f[3], sc[3], bs[3]), 0.f);
        r1.x = fmaxf(fmaf(f[4], sc[4], bs[4]), 0.f);
        r1.y = fmaxf(fmaf(f[5], sc[5], bs[5]), 0.f);
        r1.z = fmaxf(fmaf(f[6], sc[6], bs[6]), 0.f);
        r1.w = fmaxf(fmaf(f[7], sc[7], bs[7]), 0.f);
        o4[2 * i] = r0;
        o4[2 * i + 1] = r1;
    }
}

extern "C" void kernel_launch(void* const* d_in, const int* in_sizes, int n_in,
                              void* d_out, int out_size, void* d_ws, size_t ws_size,
                              hipStream_t stream) {
    const float* x      = (const float*)d_in[0];
    const float* W      = (const float*)d_in[1];
    const float* gamma  = (const float*)d_in[2];
    const float* beta   = (const float*)d_in[3];
    const int*   in_idx = (const int*)d_in[4];
    const int*   out_idx= (const int*)d_in[5];
    float* out = (float*)d_out;

    // Workspace layout (~42 MB). hist+cursor (25.6 MB) are DEAD after
    // fill_kernel and are reused as the swizzled bf16 x copy (xconv).
    auto al = [](size_t v) { return (v + 255) & ~(size_t)255; };
    size_t off = 0;
    const size_t entries_off = off; off += al((size_t)(KM + 64) * 4);
    const size_t partial_off = off; off += al((size_t)N_OUT_PTS * 4);
    const size_t zero_start  = off;
    const size_t hist_off    = off; off += al((size_t)N_OUT_PTS * 32);
    const size_t cursor_off  = off; off += al((size_t)N_OUT_PTS * 32);
    const size_t bsum_off    = off; off += al(512 * 4);
    const size_t boff_off    = off; off += al(512 * 4);
    const size_t stats_off   = off; off += al(2 * C_CH * sizeof(float));
    const size_t zero_end    = off;
    const size_t pstats_off  = off; off += al((size_t)GBLOCKS * 128 * 4);
    const size_t packB_off   = off; off += al((size_t)K_OFF * 64 * 128);
    const size_t NEEDED = off;

    if (ws_size >= NEEDED) {
        char* wsb = (char*)d_ws;
        int*      entries = (int*)(wsb + entries_off);
        int*      partial = (int*)(wsb + partial_off);
        unsigned* hist    = (unsigned*)(wsb + hist_off);
        unsigned* cursor  = (unsigned*)(wsb + cursor_off);
        int*      bsum    = (int*)(wsb + bsum_off);
        int*      boff    = (int*)(wsb + boff_off);
        float*    stats   = (float*)(wsb + stats_off);
        float*    pstats  = (float*)(wsb + pstats_off);
        unsigned short* packB = (unsigned short*)(wsb + packB_off);
        unsigned short* x16   = (unsigned short*)(wsb + hist_off);  // reuse

        (void)hipMemsetAsync(wsb + zero_start, 0, zero_end - zero_start, stream);
        (void)hipMemsetAsync(entries + KM, 0, 64 * sizeof(int), stream);

        prepack_B<<<K_OFF, 64, 0, stream>>>(W, packB);
        hist_kernel<<<(KM + 255) / 256, 256, 0, stream>>>(out_idx, hist);
        scan_a<<<SCAN_BLOCKS, 256, 0, stream>>>(hist, partial, bsum);
        scan_b<<<1, 512, 0, stream>>>(bsum, boff);
        fill_kernel<<<(KM + 255) / 256, 256, 0, stream>>>(
            out_idx, in_idx, hist, cursor, partial, boff, entries);
        xconv<<<(200000 * 4 + 255) / 256, 256, 0, stream>>>(x, x16);
        gather_bn_fused<<<GBLOCKS, 256, 0, stream>>>(
            x16, packB, entries, partial, boff, out, pstats);
        stats_reduce<<<128, 256, 0, stream>>>(pstats, stats);
        bn_apply_f32<<<2048, 256, 0, stream>>>(out, stats, gamma, beta);
    } else {
        __hip_bfloat16* out_ws = (__hip_bfloat16*)d_ws;
        const size_t acc_elems = (size_t)N_OUT_PTS * C_CH;
        float* stats = (float*)((char*)d_ws + acc_elems * sizeof(__hip_bfloat16));
        const size_t clear_bytes = acc_elems * sizeof(__hip_bfloat16) + 2 * C_CH * sizeof(float);
        (void)hipMemsetAsync(d_ws, 0, clear_bytes, stream);
        scatter_gemm_fb<<<dim3(FB_BLKX, K_OFF), 256, 0, stream>>>(x, W, in_idx, out_idx, out_ws);
        bn_stats_fb<<<2048, 256, 0, stream>>>(out_ws, stats);
        bn_apply_fb<<<2048, 256, 0, stream>>>(out_ws, stats, gamma, beta, out);
    }
}